// Round 1
// baseline (423.162 us; speedup 1.0000x reference)
//
#include <hip/hip_runtime.h>

typedef int v4i __attribute__((ext_vector_type(4)));

#define NIMG 32
#define CIN 256
#define COUT 256
#define HW   3136   // 56*56
#define W56  56

#define XQ_BYTES (NIMG * HW * CIN)          // 25,690,112
#define WP_BYTES (9 * COUT * CIN)           // 589,824

// ---------------------------------------------------------------------------
// Kernel 1: quantize + transpose  NCHW f32 -> NHWC int8
// x_int = rint(clamp(x,-1,1)*127)  (round-half-even matches jnp.round)
// Tiled 64c x 64p transpose through LDS so reads (along w) and writes
// (along c, packed uchar4) are both coalesced.
// ---------------------------------------------------------------------------
__global__ __launch_bounds__(256) void quantize_nchw_to_nhwc(
    const float* __restrict__ x, signed char* __restrict__ xq)
{
    __shared__ int tile[64][65];
    const int n  = blockIdx.z;
    const int c0 = blockIdx.y * 64;
    const int p0 = blockIdx.x * 64;
    const int tid = threadIdx.x;

    // read phase: lanes along pixels (coalesced f32)
    const int px   = tid & 63;
    const int crow = tid >> 6;          // 0..3
    const float* xb = x + ((size_t)(n * CIN + c0)) * HW + p0;
#pragma unroll
    for (int i = 0; i < 16; ++i) {
        int c = crow + i * 4;
        float v = xb[(size_t)c * HW + px];
        v = fminf(fmaxf(v, -1.f), 1.f);
        tile[c][px] = (int)rintf(v * 127.f);
    }
    __syncthreads();

    // write phase: lanes along channels, 4 channels packed per int
    const int c4   = tid & 15;          // which uchar4 within 64 channels
    const int prow = tid >> 4;          // 0..15
#pragma unroll
    for (int i = 0; i < 4; ++i) {
        int p  = prow + i * 16;
        int b0 = tile[c4 * 4 + 0][p] & 255;
        int b1 = tile[c4 * 4 + 1][p] & 255;
        int b2 = tile[c4 * 4 + 2][p] & 255;
        int b3 = tile[c4 * 4 + 3][p] & 255;
        int packed = b0 | (b1 << 8) | (b2 << 16) | (b3 << 24);
        *(int*)(xq + ((size_t)(n * HW + p0 + p)) * CIN + c0 + c4 * 4) = packed;
    }
}

// ---------------------------------------------------------------------------
// Kernel 2: weight repack  OIHW int32{-1,0,1} -> [tap][cout][cin] int8
// ---------------------------------------------------------------------------
__global__ __launch_bounds__(256) void repack_w(
    const int* __restrict__ wq, signed char* __restrict__ wp)
{
    int idx = blockIdx.x * 256 + threadIdx.x;    // < 589824
    int t   = idx >> 16;                          // /(256*256)
    int rem = idx & 65535;
    int co  = rem >> 8;
    int ci  = rem & 255;
    wp[idx] = (signed char)wq[(co * CIN + ci) * 9 + t];
}

// ---------------------------------------------------------------------------
// Kernel 3: implicit-GEMM ternary conv via mfma_i32_16x16x64_i8
// Block: 256 thr = 4 waves (2x2). Tile: 64 cout x 64 pixels.
// K-loop: 9 taps x 4 chunks of 64 cin. Fragments straight from global
// (xq fits L2; weights L2-resident). Border pixels -> zero B fragment.
// ---------------------------------------------------------------------------
__global__ __launch_bounds__(256) void bitconv_mfma(
    const signed char* __restrict__ xq, const signed char* __restrict__ wp,
    const float* __restrict__ s, const float* __restrict__ bias,
    const float* __restrict__ act_s_p, float* __restrict__ out)
{
    const int lane = threadIdx.x & 63;
    const int wid  = threadIdx.x >> 6;
    const int wr   = wid >> 1;          // 0..1 (cout half)
    const int wc   = wid & 1;           // 0..1 (pixel half)
    const int l15  = lane & 15;
    const int kg   = lane >> 4;         // 0..3 (k-group of 16 within 64)

    const int ptile = blockIdx.x;       // 0..1567
    const int n     = ptile / 49;
    const int hw0   = (ptile % 49) * 64;
    const int cout0 = blockIdx.y * 64;

    // output-pixel coordinates for the two B fragments
    int ohv[2], owv[2];
#pragma unroll
    for (int bf = 0; bf < 2; ++bf) {
        int hw  = hw0 + wc * 32 + bf * 16 + l15;
        ohv[bf] = hw / W56;
        owv[bf] = hw % W56;
    }

    v4i acc[2][2] = {};

#pragma unroll
    for (int kh = 0; kh < 3; ++kh) {
#pragma unroll
        for (int kw = 0; kw < 3; ++kw) {
            const int t = kh * 3 + kw;
            const signed char* wt  = wp + ((size_t)(t * COUT + cout0)) * CIN;
            const signed char* a0p = wt + (size_t)(wr * 32 + l15) * CIN + kg * 16;
            const signed char* a1p = a0p + 16 * CIN;

            bool valid[2];
            const signed char* bp[2];
#pragma unroll
            for (int bf = 0; bf < 2; ++bf) {
                int ih = ohv[bf] + kh - 1;
                int iw = owv[bf] + kw - 1;
                valid[bf] = ((unsigned)ih < 56u) && ((unsigned)iw < 56u);
                bp[bf] = xq + ((size_t)(n * HW + ih * W56 + iw)) * CIN + kg * 16;
            }

#pragma unroll
            for (int kc = 0; kc < 4; ++kc) {
                v4i a0 = *(const v4i*)(a0p + kc * 64);
                v4i a1 = *(const v4i*)(a1p + kc * 64);
                v4i b0 = {}; v4i b1 = {};
                if (valid[0]) b0 = *(const v4i*)(bp[0] + kc * 64);
                if (valid[1]) b1 = *(const v4i*)(bp[1] + kc * 64);
                acc[0][0] = __builtin_amdgcn_mfma_i32_16x16x64_i8(a0, b0, acc[0][0], 0, 0, 0);
                acc[0][1] = __builtin_amdgcn_mfma_i32_16x16x64_i8(a0, b1, acc[0][1], 0, 0, 0);
                acc[1][0] = __builtin_amdgcn_mfma_i32_16x16x64_i8(a1, b0, acc[1][0], 0, 0, 0);
                acc[1][1] = __builtin_amdgcn_mfma_i32_16x16x64_i8(a1, b1, acc[1][1], 0, 0, 0);
            }
        }
    }

    // epilogue: y = acc * (act_s * s[c]) + bias[c]
    const float a_s = act_s_p[0];
#pragma unroll
    for (int af = 0; af < 2; ++af) {
#pragma unroll
        for (int bf = 0; bf < 2; ++bf) {
            int hw = hw0 + wc * 32 + bf * 16 + l15;
            int cb = cout0 + wr * 32 + af * 16 + kg * 4;
#pragma unroll
            for (int r = 0; r < 4; ++r) {
                int c = cb + r;
                float y = (float)acc[af][bf][r] * (a_s * s[c]) + bias[c];
                out[((size_t)(n * COUT + c)) * HW + hw] = y;
            }
        }
    }
}

// ---------------------------------------------------------------------------
extern "C" void kernel_launch(void* const* d_in, const int* in_sizes, int n_in,
                              void* d_out, int out_size, void* d_ws, size_t ws_size,
                              hipStream_t stream)
{
    const float* x     = (const float*)d_in[0];
    const int*   w_q   = (const int*)d_in[1];     // int inputs arrive as int32
    const float* s     = (const float*)d_in[2];
    const float* bias  = (const float*)d_in[3];
    const float* act_s = (const float*)d_in[4];

    signed char* xq = (signed char*)d_ws;
    signed char* wp = (signed char*)d_ws + XQ_BYTES;

    quantize_nchw_to_nhwc<<<dim3(49, 4, NIMG), 256, 0, stream>>>(x, xq);
    repack_w<<<dim3(WP_BYTES / 256), 256, 0, stream>>>(w_q, wp);
    bitconv_mfma<<<dim3(NIMG * 49, COUT / 64), 256, 0, stream>>>(
        xq, wp, s, bias, act_s, (float*)d_out);
}

// Round 2
// 115.629 us; speedup vs baseline: 3.6597x; 3.6597x over previous
//
#include <hip/hip_runtime.h>

typedef int v4i __attribute__((ext_vector_type(4)));

#define NIMG 32
#define CIN  256
#define COUT 256
#define HW   3136   // 56*56
#define W56  56
#define HP   58     // padded H/W
#define PIMG (HP * HP)                       // 3364
#define XQP_BYTES (NIMG * PIMG * CIN)        // 27,557,888
#define WP_BYTES  (9 * COUT * CIN)           // 589,824

// ---------------------------------------------------------------------------
// Kernel 0: zero the padded activation buffer (borders must be 0)
// ---------------------------------------------------------------------------
__global__ __launch_bounds__(256) void zero_ws(v4i* __restrict__ p, int n16)
{
    int i = blockIdx.x * 256 + threadIdx.x;
    if (i < n16) { v4i z = {0, 0, 0, 0}; p[i] = z; }
}

// ---------------------------------------------------------------------------
// Kernel 1: quantize + transpose  NCHW f32 -> padded NHWC int8
// x_int = rint(clamp(x,-1,1)*127); writes interior of [n][58][58][256]
// ---------------------------------------------------------------------------
__global__ __launch_bounds__(256) void quantize_pad(
    const float* __restrict__ x, signed char* __restrict__ xqp)
{
    __shared__ int tile[64][65];
    const int n  = blockIdx.z;
    const int c0 = blockIdx.y * 64;
    const int p0 = blockIdx.x * 64;
    const int tid = threadIdx.x;

    const int px   = tid & 63;
    const int crow = tid >> 6;          // 0..3
    const float* xb = x + ((size_t)(n * CIN + c0)) * HW + p0;
#pragma unroll
    for (int i = 0; i < 16; ++i) {
        int c = crow + i * 4;
        float v = xb[(size_t)c * HW + px];
        v = fminf(fmaxf(v, -1.f), 1.f);
        tile[c][px] = (int)rintf(v * 127.f);
    }
    __syncthreads();

    const int c4   = tid & 15;          // uchar4 index within 64 channels
    const int prow = tid >> 4;          // 0..15
#pragma unroll
    for (int i = 0; i < 4; ++i) {
        int p  = prow + i * 16;
        int hw = p0 + p;
        int oh = hw / W56, ow = hw % W56;
        int b0 = tile[c4 * 4 + 0][p] & 255;
        int b1 = tile[c4 * 4 + 1][p] & 255;
        int b2 = tile[c4 * 4 + 2][p] & 255;
        int b3 = tile[c4 * 4 + 3][p] & 255;
        int packed = b0 | (b1 << 8) | (b2 << 16) | (b3 << 24);
        *(int*)(xqp + ((size_t)(n * PIMG + (oh + 1) * HP + (ow + 1))) * CIN
                    + c0 + c4 * 4) = packed;
    }
}

// ---------------------------------------------------------------------------
// Kernel 2: weight repack  OIHW int32{-1,0,1} -> [tap][kc][cout][64] int8
// so each k-step's A tile (128 cout x 64 cin) is contiguous
// ---------------------------------------------------------------------------
__global__ __launch_bounds__(256) void repack_w(
    const int* __restrict__ wq, signed char* __restrict__ wp2)
{
    int idx  = blockIdx.x * 256 + threadIdx.x;   // < 589824
    int t    = idx >> 16;                        // tap
    int rem  = idx & 65535;
    int kc   = rem >> 14;                        // 0..3
    int rem2 = rem & 16383;
    int co   = rem2 >> 6;
    int c6   = rem2 & 63;
    int ci   = kc * 64 + c6;
    wp2[idx] = (signed char)wq[(co * CIN + ci) * 9 + t];
}

// ---------------------------------------------------------------------------
// Kernel 3: implicit-GEMM ternary conv, LDS double-buffered, global_load_lds
// Tile: 128 cout x 128 px, K-step 64 (9 taps x 4 chunks = 36 steps).
// 4 waves (2x2), per-wave 4x4 16x16 frags, mfma_i32_16x16x64_i8.
// ---------------------------------------------------------------------------
__device__ __forceinline__ void gll16(const void* g, void* l)
{
    __builtin_amdgcn_global_load_lds(
        (const __attribute__((address_space(1))) int*)g,
        (__attribute__((address_space(3))) int*)l, 16, 0, 0);
}

__global__ __launch_bounds__(256, 2) void bitconv_mfma(
    const signed char* __restrict__ xqp, const signed char* __restrict__ wp2,
    const float* __restrict__ s, const float* __restrict__ bias,
    const float* __restrict__ act_s_p, float* __restrict__ out)
{
    __shared__ signed char As[2][8192];
    __shared__ signed char Bs[2][8192];

    const int tid  = threadIdx.x;
    const int lane = tid & 63;
    const int wid  = tid >> 6;
    const int wr   = wid >> 1;          // cout half
    const int wc   = wid & 1;           // pixel half
    const int l15  = lane & 15;
    const int kg   = lane >> 4;         // k-group of 16B within 64

    const int px0   = blockIdx.x * 128;
    const int cout0 = blockIdx.y * 128;

    // A staging source (linear copy): src = wp2 + step*16384 + cout0*64 + ldsoff
    const signed char* asrc = wp2 + (size_t)cout0 * 64 + wid * 2048 + lane * 16;

    // B staging: this thread's two pixels (16 pixels per wave-load, 64B each)
    const int p0 = px0 + wid * 32 + (lane >> 2);
    const int p1 = p0 + 16;
    int n0 = p0 / HW, q0 = p0 % HW, oh0 = q0 / W56, ow0 = q0 % W56;
    int n1 = p1 / HW, q1 = p1 % HW, oh1 = q1 / W56, ow1 = q1 % W56;
    const signed char* bsrc0 = xqp
        + ((size_t)(n0 * PIMG + (oh0 + 1) * HP + (ow0 + 1))) * CIN + (lane & 3) * 16;
    const signed char* bsrc1 = xqp
        + ((size_t)(n1 * PIMG + (oh1 + 1) * HP + (ow1 + 1))) * CIN + (lane & 3) * 16;

    v4i acc[4][4] = {};

    auto stage = [&](int buf, int step) {
        int t  = step >> 2, kc = step & 3;
        int dh = t / 3 - 1, dw = t % 3 - 1;
        int boff = (dh * HP + dw) * CIN + kc * 64;
        const signed char* a = asrc + step * 16384;
        gll16(a,           As[buf] + wid * 2048);
        gll16(a + 1024,    As[buf] + wid * 2048 + 1024);
        gll16(bsrc0 + boff, Bs[buf] + wid * 2048);
        gll16(bsrc1 + boff, Bs[buf] + wid * 2048 + 1024);
    };

    stage(0, 0);
    __syncthreads();

    for (int step = 0; step < 36; ++step) {
        const int cur = step & 1;
        if (step < 35) stage(cur ^ 1, step + 1);

        v4i a[4], b[4];
#pragma unroll
        for (int i = 0; i < 4; ++i) {
            a[i] = *(const v4i*)(As[cur] + ((wr * 64 + i * 16 + l15) * 64 + kg * 16));
            b[i] = *(const v4i*)(Bs[cur] + ((wc * 64 + i * 16 + l15) * 64 + kg * 16));
        }
#pragma unroll
        for (int i = 0; i < 4; ++i)
#pragma unroll
            for (int j = 0; j < 4; ++j)
                acc[i][j] = __builtin_amdgcn_mfma_i32_16x16x64_i8(
                    a[i], b[j], acc[i][j], 0, 0, 0);

        __syncthreads();   // drains vmcnt (next buf staged) + frees cur buf
    }

    // epilogue: y = acc * (act_s * s[c]) + bias[c], NCHW f32 output
    const float a_s = act_s_p[0];
    int nn[4], hh[4];
#pragma unroll
    for (int j = 0; j < 4; ++j) {
        int op = px0 + wc * 64 + j * 16 + l15;
        nn[j] = op / HW;
        hh[j] = op % HW;
    }
#pragma unroll
    for (int i = 0; i < 4; ++i) {
        int cb = cout0 + wr * 64 + i * 16 + kg * 4;
        float sc[4], bi[4];
#pragma unroll
        for (int r = 0; r < 4; ++r) {
            sc[r] = a_s * s[cb + r];
            bi[r] = bias[cb + r];
        }
#pragma unroll
        for (int j = 0; j < 4; ++j)
#pragma unroll
            for (int r = 0; r < 4; ++r)
                out[((size_t)(nn[j] * COUT + cb + r)) * HW + hh[j]] =
                    (float)acc[i][j][r] * sc[r] + bi[r];
    }
}

// ---------------------------------------------------------------------------
extern "C" void kernel_launch(void* const* d_in, const int* in_sizes, int n_in,
                              void* d_out, int out_size, void* d_ws, size_t ws_size,
                              hipStream_t stream)
{
    const float* x     = (const float*)d_in[0];
    const int*   w_q   = (const int*)d_in[1];
    const float* s     = (const float*)d_in[2];
    const float* bias  = (const float*)d_in[3];
    const float* act_s = (const float*)d_in[4];

    signed char* xqp = (signed char*)d_ws;
    signed char* wp2 = (signed char*)d_ws + XQP_BYTES;

    zero_ws<<<XQP_BYTES / 16 / 256, 256, 0, stream>>>((v4i*)xqp, XQP_BYTES / 16);
    quantize_pad<<<dim3(49, 4, NIMG), 256, 0, stream>>>(x, xqp);
    repack_w<<<dim3(WP_BYTES / 256), 256, 0, stream>>>(w_q, wp2);
    bitconv_mfma<<<dim3(784, 2), 256, 0, stream>>>(
        xqp, wp2, s, bias, act_s, (float*)d_out);
}

// Round 3
// 101.031 us; speedup vs baseline: 4.1884x; 1.1445x over previous
//
#include <hip/hip_runtime.h>

typedef int v4i __attribute__((ext_vector_type(4)));

#define NIMG 32
#define CIN  256
#define COUT 256
#define HW   3136   // 56*56
#define W56  56
#define HP   58     // padded H/W
#define PIMG (HP * HP)                       // 3364
#define XQP_BYTES (NIMG * PIMG * CIN)        // 27,557,888
#define WP_BYTES  (9 * COUT * CIN)           // 589,824

#define BARRIER() asm volatile("s_barrier" ::: "memory")
#define VMCNT(n)  asm volatile("s_waitcnt vmcnt(" #n ")" ::: "memory")

// ---------------------------------------------------------------------------
// Kernel 0: zero only the pad border (228 px/image * 256B)
// ---------------------------------------------------------------------------
__global__ __launch_bounds__(256) void zero_border(v4i* __restrict__ p)
{
    int i = blockIdx.x * 256 + threadIdx.x;
    if (i >= NIMG * 228 * 16) return;
    int n = i / 3648, r = i % 3648, pix = r >> 4, c = r & 15;
    int h, w;
    if (pix < 58)       { h = 0;         w = pix;       }
    else if (pix < 116) { h = 57;        w = pix - 58;  }
    else if (pix < 172) { h = pix - 115; w = 0;         }
    else                { h = pix - 171; w = 57;        }
    v4i z = {0, 0, 0, 0};
    p[(size_t)(n * PIMG + h * HP + w) * 16 + c] = z;
}

// ---------------------------------------------------------------------------
// Kernel 1: quantize + transpose  NCHW f32 -> padded NHWC int8 (interior)
// ---------------------------------------------------------------------------
__global__ __launch_bounds__(256) void quantize_pad(
    const float* __restrict__ x, signed char* __restrict__ xqp)
{
    __shared__ int tile[64][65];
    const int n  = blockIdx.z;
    const int c0 = blockIdx.y * 64;
    const int p0 = blockIdx.x * 64;
    const int tid = threadIdx.x;

    const int px   = tid & 63;
    const int crow = tid >> 6;
    const float* xb = x + ((size_t)(n * CIN + c0)) * HW + p0;
#pragma unroll
    for (int i = 0; i < 16; ++i) {
        int c = crow + i * 4;
        float v = xb[(size_t)c * HW + px];
        v = fminf(fmaxf(v, -1.f), 1.f);
        tile[c][px] = (int)rintf(v * 127.f);
    }
    __syncthreads();

    const int c4   = tid & 15;
    const int prow = tid >> 4;
#pragma unroll
    for (int i = 0; i < 4; ++i) {
        int p  = prow + i * 16;
        int hw = p0 + p;
        int oh = hw / W56, ow = hw % W56;
        int b0 = tile[c4 * 4 + 0][p] & 255;
        int b1 = tile[c4 * 4 + 1][p] & 255;
        int b2 = tile[c4 * 4 + 2][p] & 255;
        int b3 = tile[c4 * 4 + 3][p] & 255;
        int packed = b0 | (b1 << 8) | (b2 << 16) | (b3 << 24);
        *(int*)(xqp + ((size_t)(n * PIMG + (oh + 1) * HP + (ow + 1))) * CIN
                    + c0 + c4 * 4) = packed;
    }
}

// ---------------------------------------------------------------------------
// Kernel 2: weight repack  OIHW int32{-1,0,1} -> [step 0..35][cout 256][64B]
// ---------------------------------------------------------------------------
__global__ __launch_bounds__(256) void repack_w(
    const int* __restrict__ wq, signed char* __restrict__ wp2)
{
    int idx  = blockIdx.x * 256 + threadIdx.x;   // < 589824
    int t    = idx >> 16;
    int rem  = idx & 65535;
    int kc   = rem >> 14;
    int rem2 = rem & 16383;
    int co   = rem2 >> 6;
    int c6   = rem2 & 63;
    int ci   = kc * 64 + c6;
    wp2[idx] = (signed char)wq[(co * CIN + ci) * 9 + t];
}

// ---------------------------------------------------------------------------
// Kernel 3: phased implicit-GEMM conv. Tile 128 cout x 256 px, BK=64,
// 8 waves (2x4), 3-deep LDS pipeline, counted vmcnt, swizzled LDS,
// setprio around MFMA clusters.
// ---------------------------------------------------------------------------
__device__ __forceinline__ void gll16(const void* g, void* l)
{
    __builtin_amdgcn_global_load_lds(
        (const __attribute__((address_space(1))) int*)g,
        (__attribute__((address_space(3))) int*)l, 16, 0, 0);
}

__global__ __launch_bounds__(512) void bitconv_mfma(
    const signed char* __restrict__ xqp, const signed char* __restrict__ wp2,
    const float* __restrict__ s_, const float* __restrict__ bias,
    const float* __restrict__ act_s_p, float* __restrict__ out)
{
    // per buffer: A 8KB (128 cout x 64B), B 16KB (256 px x 64B)
    __shared__ signed char lds[3][24576];

    const int tid  = threadIdx.x;
    const int lane = tid & 63;
    const int wid  = tid >> 6;
    const int wr   = wid >> 2;          // 0..1  cout half
    const int wc   = wid & 3;           // 0..3  px quarter
    const int l15  = lane & 15;
    const int kg   = lane >> 4;
    const int kgs  = ((kg ^ ((l15 >> 1) & 3)) << 4);   // swizzled chunk

    // XCD-bijective swizzle (784 % 8 == 0): pair cout-halves on one XCD
    const int b  = blockIdx.x;
    const int w  = (b & 7) * 98 + (b >> 3);
    const int px0   = (w >> 1) * 256;
    const int cout0 = (w & 1) * 128;

    // ---- staging addresses (swizzle baked into the global source) ----
    const int srow   = tid >> 2;                         // 0..127
    const int schunk = (((tid & 3) ^ ((tid >> 3) & 3)) << 4);
    const signed char* asrc = wp2 + cout0 * 64 + srow * 64 + schunk;

    const int pA = px0 + srow, pB = pA + 128;
    const int nA = pA / HW, qA = pA % HW;
    const int nB = pB / HW, qB = pB % HW;
    const signed char* bsrc0 = xqp
        + ((size_t)(nA * PIMG + (qA / W56 + 1) * HP + (qA % W56 + 1))) * CIN + schunk;
    const signed char* bsrc1 = xqp
        + ((size_t)(nB * PIMG + (qB / W56 + 1) * HP + (qB % W56 + 1))) * CIN + schunk;

    // ---- fragment ds_read offsets (swizzled) ----
    int aoff[4], boff[4];
#pragma unroll
    for (int i = 0; i < 4; ++i)
        aoff[i] = (wr * 64 + i * 16 + l15) * 64 + kgs;
#pragma unroll
    for (int j = 0; j < 4; ++j)
        boff[j] = 8192 + (wc * 64 + j * 16 + l15) * 64 + kgs;

    v4i acc[4][4] = {};

    auto stage = [&](int buf, int s) {
        int t9 = s >> 2, kc = s & 3;
        int bo = ((t9 / 3 - 1) * HP + (t9 % 3 - 1)) * CIN + kc * 64;
        signed char* L = &lds[buf][0];
        gll16(asrc + s * 16384, L + wid * 1024);
        gll16(bsrc0 + bo,       L + 8192  + wid * 1024);
        gll16(bsrc1 + bo,       L + 16384 + wid * 1024);
    };

    // prologue: steps 0 and 1 staged; wait step 0's 3 loads (3 stay in flight)
    stage(0, 0);
    stage(1, 1);
    VMCNT(3);
    BARRIER();

    for (int it = 0; it < 12; ++it) {
#pragma unroll
        for (int u = 0; u < 3; ++u) {
            const int s = it * 3 + u;
            const signed char* L = &lds[u][0];

            v4i a[4], bb[4];
#pragma unroll
            for (int i = 0; i < 4; ++i) a[i]  = *(const v4i*)(L + aoff[i]);
#pragma unroll
            for (int j = 0; j < 4; ++j) bb[j] = *(const v4i*)(L + boff[j]);

            if (s <= 33) stage((u + 2) % 3, s + 2);   // uniform branch

            BARRIER();                 // all reads/stages issued
            __builtin_amdgcn_s_setprio(1);
#pragma unroll
            for (int i = 0; i < 2; ++i)
#pragma unroll
                for (int j = 0; j < 4; ++j)
                    acc[i][j] = __builtin_amdgcn_mfma_i32_16x16x64_i8(
                        a[i], bb[j], acc[i][j], 0, 0, 0);
            __builtin_amdgcn_s_setprio(0);

            BARRIER();                 // phase split (role diversity)
            __builtin_amdgcn_s_setprio(1);
#pragma unroll
            for (int i = 2; i < 4; ++i)
#pragma unroll
                for (int j = 0; j < 4; ++j)
                    acc[i][j] = __builtin_amdgcn_mfma_i32_16x16x64_i8(
                        a[i], bb[j], acc[i][j], 0, 0, 0);
            __builtin_amdgcn_s_setprio(0);

            // counted vmcnt: next step's 3 loads done, newest 3 stay in flight
            if (s <= 33)      { VMCNT(3); }
            else if (s == 34) { VMCNT(0); }
            if (s < 35) BARRIER();
        }
    }

    // ---- epilogue: y = acc * (act_s * s[c]) + bias[c], NCHW f32 ----
    const float a_s = act_s_p[0];
    int nn[4], hh[4];
#pragma unroll
    for (int j = 0; j < 4; ++j) {
        int op = px0 + wc * 64 + j * 16 + l15;
        nn[j] = op / HW;
        hh[j] = op % HW;
    }
#pragma unroll
    for (int i = 0; i < 4; ++i) {
        int cb = cout0 + wr * 64 + i * 16 + kg * 4;
        float sc[4], bi[4];
#pragma unroll
        for (int r = 0; r < 4; ++r) {
            sc[r] = a_s * s_[cb + r];
            bi[r] = bias[cb + r];
        }
#pragma unroll
        for (int j = 0; j < 4; ++j)
#pragma unroll
            for (int r = 0; r < 4; ++r)
                out[((size_t)(nn[j] * COUT + cb + r)) * HW + hh[j]] =
                    (float)acc[i][j][r] * sc[r] + bi[r];
    }
}

// ---------------------------------------------------------------------------
extern "C" void kernel_launch(void* const* d_in, const int* in_sizes, int n_in,
                              void* d_out, int out_size, void* d_ws, size_t ws_size,
                              hipStream_t stream)
{
    const float* x     = (const float*)d_in[0];
    const int*   w_q   = (const int*)d_in[1];
    const float* s     = (const float*)d_in[2];
    const float* bias  = (const float*)d_in[3];
    const float* act_s = (const float*)d_in[4];

    signed char* xqp = (signed char*)d_ws;
    signed char* wp2 = (signed char*)d_ws + XQP_BYTES;

    zero_border<<<(NIMG * 228 * 16 + 255) / 256, 256, 0, stream>>>((v4i*)xqp);
    quantize_pad<<<dim3(49, 4, NIMG), 256, 0, stream>>>(x, xqp);
    repack_w<<<dim3(WP_BYTES / 256), 256, 0, stream>>>(w_q, wp2);
    bitconv_mfma<<<dim3(784), 512, 0, stream>>>(
        xqp, wp2, s, bias, act_s, (float*)d_out);
}